// Round 11
// baseline (328.150 us; speedup 1.0000x reference)
//
#include <hip/hip_runtime.h>
#include <stdint.h>
#include <string.h>

#define BB 256
#define TT 2048
#define DD 64
#define CC 128         // chunks per chain
#define SS 16          // steps per chunk
#define C_L2E 1.44269504f
#define C_LN2 0.69314718f
// log2(1 + 2^-9): compensates bf16 truncation bias of the pack, folded into exp
#define C_BIAS 0.0028174f

typedef short sh8  __attribute__((ext_vector_type(8)));
typedef float f32x4 __attribute__((ext_vector_type(4)));

union BU { sh8 v8; unsigned int u[4]; unsigned short s[8]; };

__device__ __forceinline__ float expf_fast(float x) { return __builtin_amdgcn_exp2f(x * C_L2E); }
__device__ __forceinline__ unsigned short bf16rne(float x) {
    unsigned int u = __float_as_uint(x);
    u += 0x7FFF + ((u >> 16) & 1u);
    return (unsigned short)(u >> 16);
}
__device__ __forceinline__ unsigned int pkbf(float hi, float lo) {
    return __builtin_amdgcn_perm(__float_as_uint(hi), __float_as_uint(lo), 0x07060302u);
}

#define DPPMAX(x, ctrl, rm, bm) { int _xi = __float_as_int(x);                              \
    int _yi = __builtin_amdgcn_update_dpp(_xi, _xi, ctrl, rm, bm, false);                   \
    x = fmaxf(x, __int_as_float(_yi)); }

// ---------- kernel 0: precompute MFMA A-fragments for both directions ----------
// Layout: wsF[((dir*8 + mt*2 + kt2) * 64 + lane) * 4 .. +3] (uint4 per lane, coalesced)
__global__ __launch_bounds__(128) void crf_frag(
    const float* __restrict__ tr, unsigned int* __restrict__ wsF)
{
    const int tid = threadIdx.x, bwd = tid >> 6, lane = tid & 63;
    const int q = lane >> 4, ml = lane & 15;
#pragma unroll
    for (int mt = 0; mt < 4; ++mt)
#pragma unroll
        for (int kt2 = 0; kt2 < 2; ++kt2) {
            BU a;
#pragma unroll
            for (int j = 0; j < 8; ++j) {
                int lam = 32 * kt2 + 16 * (j >> 2) + 4 * q + (j & 3);
                float tv = bwd ? tr[(16 * mt + ml) * DD + lam] : tr[lam * DD + 16 * mt + ml];
                a.s[j] = (short)bf16rne(expf_fast(tv));
            }
            uint4 pk; pk.x = a.u[0]; pk.y = a.u[1]; pk.z = a.u[2]; pk.w = a.u[3];
            *(uint4*)(wsF + ((size_t)(bwd * 8 + mt * 2 + kt2) * 64 + lane) * 4) = pk;
        }
}

// ---------- kernel 1: scores + lengths; partial sums per (chain, 256-token block) ----------
__global__ __launch_bounds__(256) void crf_score(
    const float* __restrict__ p, const int* __restrict__ y,
    const int* __restrict__ mask, const float* __restrict__ tr,
    float* __restrict__ wsS8, int* __restrict__ wsL8)
{
    __shared__ int mk[257];
    __shared__ unsigned char labs[257];
    __shared__ float redf[4];
    __shared__ int redi[4];
    const int c = blockIdx.y, bx = blockIdx.x, t0 = bx * 256;
    const int tid = threadIdx.x;
    const int g = tid & 15, sub = tid >> 4;
    const size_t cb = (size_t)c * TT;

    mk[tid] = mask[cb + t0 + tid];
    if (tid == 0) mk[256] = (t0 + 256 < TT) ? mask[cb + t0 + 256] : 1;
    __syncthreads();

    // issue ALL y loads unconditionally (padding rows are valid memory) for max MLP
    int4 v[16];
#pragma unroll
    for (int k = 0; k < 16; ++k)
        v[k] = ((const int4*)y)[(cb + t0 + k * 16 + sub) * 16 + g];

    float s1 = 0.f;
    int vc = 0;
#pragma unroll
    for (int k = 0; k < 16; ++k) {
        const int ti = k * 16 + sub;
        int cand = v[k].w ? 4 * g + 3 : v[k].z ? 4 * g + 2 : v[k].y ? 4 * g + 1 : v[k].x ? 4 * g : -1;
#pragma unroll
        for (int xm = 1; xm <= 8; xm <<= 1) {
            int o = __shfl_xor(cand, xm, 16);
            cand = o > cand ? o : cand;
        }
        if (g == 0 && mk[ti] == 0) {
            labs[ti] = (unsigned char)cand;
            s1 += p[(cb + t0 + ti) * DD + cand];
            vc += 1;
        }
    }
    if (tid < 16 && mk[256] == 0) {             // boundary label t0+256
        int4 vb = ((const int4*)y)[(cb + t0 + 256) * 16 + tid];
        int cand = vb.w ? 4 * tid + 3 : vb.z ? 4 * tid + 2 : vb.y ? 4 * tid + 1 : vb.x ? 4 * tid : -1;
#pragma unroll
        for (int xm = 1; xm <= 8; xm <<= 1) {
            int o = __shfl_xor(cand, xm, 16);
            cand = o > cand ? o : cand;
        }
        if (tid == 0) labs[256] = (unsigned char)cand;
    }
    __syncthreads();

    float s2 = 0.f;
    if (mk[tid + 1] == 0)                       // pair (t,t+1) valid (prefix property)
        s2 = tr[(int)labs[tid] * DD + (int)labs[tid + 1]];

    float acc = s1 + s2;
#pragma unroll
    for (int xm = 32; xm >= 1; xm >>= 1) { acc += __shfl_xor(acc, xm, 64); vc += __shfl_xor(vc, xm, 64); }
    if ((tid & 63) == 0) { redf[tid >> 6] = acc; redi[tid >> 6] = vc; }
    __syncthreads();
    if (tid == 0) {
        wsS8[c * 8 + bx] = redf[0] + redf[1] + redf[2] + redf[3];
        wsL8[c * 8 + bx] = redi[0] + redi[1] + redi[2] + redi[3];
    }
}

// ---------- kernel 2: rank-1 chunk probes (fwd: a = H q ; bwd: b = H^T 1), S=16 ----------
// Block: 4 waves = (ic,fwd),(ic,bwd),(ic+1,fwd),(ic+1,bwd) — same p slab for L2 reuse.
// Wave batches 16 chains (c = 16cg+ml). 8 MFMA/step; state f32[16]/lane, lambda-relabelled
// (lam = 32kt2+16h+4q+r) so D -> next-B is in-lane. A-fragments preloaded from wsF.
__global__ __launch_bounds__(256) void crf_probe(
    const float* __restrict__ p, const unsigned int* __restrict__ wsF,
    const int* __restrict__ wsL8,
    unsigned short* __restrict__ wsA, unsigned short* __restrict__ wsB, int* __restrict__ wsSig)
{
    const int tid = threadIdx.x, w = tid >> 6, lane = tid & 63;
    const int q = lane >> 4, ml = lane & 15;
    const int cg = blockIdx.x;
    const int ic = blockIdx.y * 2 + (w >> 1);
    const int bwd = w & 1;
    const int c = cg * 16 + ml;
    const int t0 = ic * SS, t1 = t0 + SS;
    const int ts = (ic == 0) ? 1 : t0;
    const float* prow = p + (size_t)c * TT * DD;

    // per-chain length = sum of 8 partials
    int Lml;
    {
        const int4* lp = (const int4*)(wsL8 + c * 8);
        int4 a0 = lp[0], a1 = lp[1];
        Lml = a0.x + a0.y + a0.z + a0.w + a1.x + a1.y + a1.z + a1.w;
    }

    // A fragments preloaded (8 coalesced uint4 loads)
    BU A[4][2];
#pragma unroll
    for (int mt = 0; mt < 4; ++mt)
#pragma unroll
        for (int kt2 = 0; kt2 < 2; ++kt2) {
            uint4 pk = *(const uint4*)(wsF + ((size_t)(bwd * 8 + mt * 2 + kt2) * 64 + lane) * 4);
            A[mt][kt2].u[0] = pk.x; A[mt][kt2].u[1] = pk.y; A[mt][kt2].u[2] = pk.z; A[mt][kt2].u[3] = pk.w;
        }

    // state xs[idx], idx = kt2*8 + h*4 + r  <->  lam = 32kt2+16h+4q+r
    float xs[16];
    if (!bwd && ic == 0) {           // exact start: u0 = exp(p[c,0,:])
#pragma unroll
        for (int k = 0; k < 4; ++k) {
            f32x4 v = *(const f32x4*)(prow + 16 * k + 4 * q);
#pragma unroll
            for (int r = 0; r < 4; ++r)
                xs[(k >> 1) * 8 + (k & 1) * 4 + r] = __builtin_amdgcn_exp2f(fmaf(v[r], C_L2E, C_BIAS));
        }
    } else {
#pragma unroll
        for (int i = 0; i < 16; ++i) xs[i] = 1.0f;
    }

    // wave max of L -> skip all-frozen step ranges
    int mL = Lml;
#pragma unroll
    for (int xm = 32; xm >= 1; xm >>= 1) { int o = __shfl_xor(mL, xm, 64); mL = o > mL ? o : mL; }
    int ibeg = 0, iend = SS;
    if (!bwd) { int ir = mL - t0; if (ir < 0) ir = 0; iend = (ir + 3) & ~3; if (iend > SS) iend = SS; }
    else      { int ir = t1 - mL; if (ir < 0) ir = 0; ibeg = ir & ~3; if (ibeg > SS) ibeg = SS; }

    int sig = 0;
    const f32x4 z4 = {0.f, 0.f, 0.f, 0.f};

    if (ibeg < iend) {
        f32x4 er[4][4];
#pragma unroll
        for (int s = 0; s < 4; ++s) {
            int i = ibeg + s;
            int t = bwd ? (t1 - 1 - i) : (t0 + i);
#pragma unroll
            for (int k = 0; k < 4; ++k)
                er[s][k] = *(const f32x4*)(prow + (size_t)t * DD + 16 * k + 4 * q);
        }
        for (int ib = ibeg; ib < iend; ib += 4) {
#pragma unroll
            for (int s = 0; s < 4; ++s) {
                const int i = ib + s;
                const int t = bwd ? (t1 - 1 - i) : (t0 + i);
                const bool act = (t >= ts) && (t < Lml);
                float ee[4][4];
#pragma unroll
                for (int k = 0; k < 4; ++k)
#pragma unroll
                    for (int r = 0; r < 4; ++r)
                        ee[k][r] = __builtin_amdgcn_exp2f(fmaf(er[s][k][r], C_L2E, C_BIAS));
                {   // prefetch step i+4 into slot s
                    int ipf = i + 4;
                    int tpf = bwd ? (t1 - 1 - ipf) : (t0 + ipf);
                    if (tpf < t0) tpf = t0;
                    if (tpf > t1 - 1) tpf = t1 - 1;
#pragma unroll
                    for (int k = 0; k < 4; ++k)
                        er[s][k] = *(const f32x4*)(prow + (size_t)tpf * DD + 16 * k + 4 * q);
                }
                float cand[16];
                BU Bf[2];
                f32x4 acc[4];
                if (!bwd) {     // u' = diag(e) W^T u : scale on output
#pragma unroll
                    for (int kt2 = 0; kt2 < 2; ++kt2)
#pragma unroll
                        for (int jj = 0; jj < 4; ++jj)
                            Bf[kt2].u[jj] = pkbf(xs[kt2 * 8 + 2 * jj + 1], xs[kt2 * 8 + 2 * jj]);
#pragma unroll
                    for (int mt = 0; mt < 4; ++mt) {
                        acc[mt] = __builtin_amdgcn_mfma_f32_16x16x32_bf16(A[mt][0].v8, Bf[0].v8, z4, 0, 0, 0);
                        acc[mt] = __builtin_amdgcn_mfma_f32_16x16x32_bf16(A[mt][1].v8, Bf[1].v8, acc[mt], 0, 0, 0);
                    }
#pragma unroll
                    for (int mt = 0; mt < 4; ++mt)
#pragma unroll
                        for (int r = 0; r < 4; ++r)
                            cand[(mt >> 1) * 8 + (mt & 1) * 4 + r] = acc[mt][r] * ee[mt][r];
                } else {        // w' = W (e .* w) : scale on input
                    float xsc[16];
#pragma unroll
                    for (int kt2 = 0; kt2 < 2; ++kt2)
#pragma unroll
                        for (int h = 0; h < 2; ++h)
#pragma unroll
                            for (int r = 0; r < 4; ++r)
                                xsc[kt2 * 8 + h * 4 + r] = xs[kt2 * 8 + h * 4 + r] * ee[2 * kt2 + h][r];
#pragma unroll
                    for (int kt2 = 0; kt2 < 2; ++kt2)
#pragma unroll
                        for (int jj = 0; jj < 4; ++jj)
                            Bf[kt2].u[jj] = pkbf(xsc[kt2 * 8 + 2 * jj + 1], xsc[kt2 * 8 + 2 * jj]);
#pragma unroll
                    for (int mt = 0; mt < 4; ++mt) {
                        acc[mt] = __builtin_amdgcn_mfma_f32_16x16x32_bf16(A[mt][0].v8, Bf[0].v8, z4, 0, 0, 0);
                        acc[mt] = __builtin_amdgcn_mfma_f32_16x16x32_bf16(A[mt][1].v8, Bf[1].v8, acc[mt], 0, 0, 0);
                    }
#pragma unroll
                    for (int mt = 0; mt < 4; ++mt)
#pragma unroll
                        for (int r = 0; r < 4; ++r)
                            cand[(mt >> 1) * 8 + (mt & 1) * 4 + r] = acc[mt][r];
                }
                if (s == 3) {   // wave-uniform pow-2 renorm, per-chain sig
                    float mx = fabsf(cand[0]);
#pragma unroll
                    for (int i2 = 1; i2 < 16; ++i2) mx = fmaxf(mx, fabsf(cand[i2]));
                    DPPMAX(mx, 0x111, 0xF, 0xF); DPPMAX(mx, 0x112, 0xF, 0xF);
                    DPPMAX(mx, 0x114, 0xF, 0xF); DPPMAX(mx, 0x118, 0xF, 0xF);
                    DPPMAX(mx, 0x142, 0xA, 0xF); DPPMAX(mx, 0x143, 0xC, 0xF);
                    int smx = __builtin_amdgcn_readlane(__float_as_int(mx), 63);
                    int kk = ((smx >> 23) & 255) - 127;
                    kk = kk < -124 ? -124 : (kk > 124 ? 124 : kk);
                    float sc = __int_as_float((unsigned)(127 - kk) << 23);
#pragma unroll
                    for (int i2 = 0; i2 < 16; ++i2) cand[i2] *= sc;
                    if (act) sig += kk;
                }
#pragma unroll
                for (int i2 = 0; i2 < 16; ++i2) xs[i2] = act ? cand[i2] : xs[i2];
            }
        }
    }

    unsigned short* dst = (bwd ? wsB : wsA) + ((size_t)c * CC + ic) * 64;
#pragma unroll
    for (int kt2 = 0; kt2 < 2; ++kt2)
#pragma unroll
        for (int h = 0; h < 2; ++h)
#pragma unroll
            for (int r = 0; r < 4; ++r)
                dst[32 * kt2 + 16 * h + 4 * q + r] = bf16rne(xs[kt2 * 8 + h * 4 + r]);
    if (!bwd && q == 0) wsSig[c * CC + ic] = sig;
}

// ---------- kernel 3: parallel rank-1 combine, one block per chain ----------
// logZ/ln2 = sig_0 + sum_{i>=1} [sig_i + log2(b_i.a_{i-1}) - log2(b_i.1)] + log2(1.a_{C-1})
__global__ __launch_bounds__(256) void crf_combine(
    const unsigned short* __restrict__ wsA, const unsigned short* __restrict__ wsB,
    const int* __restrict__ wsSig, const float* __restrict__ wsS8,
    float* __restrict__ out)
{
    __shared__ float eParts[4];
    const int tid = threadIdx.x, w = tid >> 6, lane = tid & 63;
    const int c = blockIdx.x;

    float Ep = 0.f;
#pragma unroll
    for (int k = 0; k < 32; ++k) {
        const int i = w * 32 + k;
        if (i == 0) continue;
        float b  = __uint_as_float((unsigned)wsB[((size_t)c * CC + i) * 64 + lane] << 16);
        float ap = __uint_as_float((unsigned)wsA[((size_t)c * CC + i - 1) * 64 + lane] << 16);
        float d1 = b * ap, d0 = b;
#pragma unroll
        for (int xm = 32; xm >= 1; xm >>= 1) { d1 += __shfl_xor(d1, xm, 64); d0 += __shfl_xor(d0, xm, 64); }
        Ep += (float)wsSig[c * CC + i] + __builtin_amdgcn_logf(d1) - __builtin_amdgcn_logf(d0);
    }
    if (w == 0) Ep += (float)wsSig[c * CC];
    if (w == 3) {
        float al = __uint_as_float((unsigned)wsA[((size_t)c * CC + CC - 1) * 64 + lane] << 16);
#pragma unroll
        for (int xm = 32; xm >= 1; xm >>= 1) al += __shfl_xor(al, xm, 64);
        Ep += __builtin_amdgcn_logf(al);
    }
    if (lane == 0) eParts[w] = Ep;
    __syncthreads();
    if (tid == 0) {
        float E = eParts[0] + eParts[1] + eParts[2] + eParts[3];
        const float4* sp = (const float4*)(wsS8 + c * 8);
        float4 s0 = sp[0], s1 = sp[1];
        float S = (s0.x + s0.y + s0.z + s0.w) + (s1.x + s1.y + s1.z + s1.w);
        out[c] = C_LN2 * E - S;
    }
}

extern "C" void kernel_launch(void* const* d_in, const int* in_sizes, int n_in,
                              void* d_out, int out_size, void* d_ws, size_t ws_size,
                              hipStream_t stream) {
    const float* p  = (const float*)d_in[0];
    const int*   y  = (const int*)d_in[1];
    const int*   mk = (const int*)d_in[2];
    const float* tr = (const float*)d_in[3];
    float* out = (float*)d_out;

    float* wsS8 = (float*)d_ws;                                          // 8 KB
    int*   wsL8 = (int*)((char*)d_ws + 8192);                            // 8 KB
    unsigned int* wsF = (unsigned int*)((char*)d_ws + 16384);            // 16 KB
    int*   wsSg = (int*)((char*)d_ws + 32768);                           // 128 KB
    unsigned short* wsA = (unsigned short*)((char*)d_ws + 163840);       // 4 MB (bf16)
    unsigned short* wsB = (unsigned short*)((char*)d_ws + 163840 + (4u << 20));  // 4 MB

    crf_frag<<<dim3(1), dim3(128), 0, stream>>>(tr, wsF);
    crf_score<<<dim3(8, BB), dim3(256), 0, stream>>>(p, y, mk, tr, wsS8, wsL8);
    crf_probe<<<dim3(16, CC / 2), dim3(256), 0, stream>>>(p, wsF, wsL8, wsA, wsB, wsSg);
    crf_combine<<<dim3(BB), dim3(256), 0, stream>>>(wsA, wsB, wsSg, wsS8, out);
}